// Round 8
// baseline (241.140 us; speedup 1.0000x reference)
//
#include <hip/hip_runtime.h>

#define NFFT 1024
#define TPB 256  // 4 waves per block
#define RPW 2    // rows per wave, software-pipelined

// ---------- complex helpers ----------
__device__ __forceinline__ float2 cmul(float2 a, float2 b) {
  return make_float2(fmaf(a.x, b.x, -a.y * b.y), fmaf(a.x, b.y, a.y * b.x));
}
__device__ __forceinline__ float2 cadd(float2 a, float2 b) { return make_float2(a.x + b.x, a.y + b.y); }
__device__ __forceinline__ float2 csub(float2 a, float2 b) { return make_float2(a.x - b.x, a.y - b.y); }

// y_k = sum_r v_r * e^{-2*pi*i*k*r/4}
__device__ __forceinline__ void dft4(const float2 v[4], float2 y[4]) {
  float2 s02 = cadd(v[0], v[2]), d02 = csub(v[0], v[2]);
  float2 s13 = cadd(v[1], v[3]), d13 = csub(v[1], v[3]);
  y[0] = cadd(s02, s13);
  y[2] = csub(s02, s13);
  y[1] = make_float2(d02.x + d13.y, d02.y - d13.x);  // d02 + (-i)*d13
  y[3] = make_float2(d02.x - d13.y, d02.y + d13.x);  // d02 + (+i)*d13
}

// ---------- DPP quad shuffles ----------
__device__ __forceinline__ float dpp_xor2(float x) {
  return __int_as_float(__builtin_amdgcn_update_dpp(0, __float_as_int(x), 0x4E, 0xF, 0xF, true));
}
__device__ __forceinline__ float dpp_xor1(float x) {
  return __int_as_float(__builtin_amdgcn_update_dpp(0, __float_as_int(x), 0xB1, 0xF, 0xF, true));
}

// ---------- in-lane 16-point FFT (verified r1-r4) ----------
// Output: slot s holds Z[KOF(s)], KOF(s) = (s>>2) | ((s&3)<<2). Twiddles compile-time.
__device__ __forceinline__ void fft16(float2 z[16]) {
  float2 g[16];
  #pragma unroll
  for (int c0 = 0; c0 < 4; ++c0) {
    float2 v[4] = {z[c0], z[c0 + 4], z[c0 + 8], z[c0 + 12]};
    float2 y[4];
    dft4(v, y);
    g[4 * c0 + 0] = y[0]; g[4 * c0 + 1] = y[1]; g[4 * c0 + 2] = y[2]; g[4 * c0 + 3] = y[3];
  }
  const float C1 = 0.92387953251128674f, S1 = 0.38268343236508978f, R = 0.70710678118654752f;
  g[5]  = cmul(g[5],  make_float2( C1, -S1));
  g[6]  = cmul(g[6],  make_float2(  R,  -R));
  g[7]  = cmul(g[7],  make_float2( S1, -C1));
  g[9]  = cmul(g[9],  make_float2(  R,  -R));
  g[10] = make_float2(g[10].y, -g[10].x);
  g[11] = cmul(g[11], make_float2( -R,  -R));
  g[13] = cmul(g[13], make_float2( S1, -C1));
  g[14] = cmul(g[14], make_float2( -R,  -R));
  g[15] = cmul(g[15], make_float2(-C1,  S1));
  #pragma unroll
  for (int k0 = 0; k0 < 4; ++k0) {
    float2 v[4] = {g[k0], g[4 + k0], g[8 + k0], g[12 + k0]};
    float2 y[4];
    dft4(v, y);
    z[4 * k0 + 0] = y[0]; z[4 * k0 + 1] = y[1]; z[4 * k0 + 2] = y[2]; z[4 * k0 + 3] = y[3];
  }
}

// z[sl(k)] *= u^k for k=1..15, sl(k) = ((k&3)<<2)|(k>>2).
// Four parallel chains advanced by u^4: dependent depth ~5 (was 15 serial).
__device__ __forceinline__ void twiddle_apply(float2 z[16], float2 u) {
  const float2 u2 = cmul(u, u);
  const float2 u4 = cmul(u2, u2);
  float2 c1 = u, c2 = u2, c3 = cmul(u2, u), c4 = u4;
  // k = 1,2,3,4 -> slots 4,8,12,1
  z[4]  = cmul(z[4],  c1); z[8]  = cmul(z[8],  c2);
  z[12] = cmul(z[12], c3); z[1]  = cmul(z[1],  c4);
  c1 = cmul(c1, u4); c2 = cmul(c2, u4); c3 = cmul(c3, u4); c4 = cmul(c4, u4);
  // k = 5,6,7,8 -> slots 5,9,13,2
  z[5]  = cmul(z[5],  c1); z[9]  = cmul(z[9],  c2);
  z[13] = cmul(z[13], c3); z[2]  = cmul(z[2],  c4);
  c1 = cmul(c1, u4); c2 = cmul(c2, u4); c3 = cmul(c3, u4); c4 = cmul(c4, u4);
  // k = 9,10,11,12 -> slots 6,10,14,3
  z[6]  = cmul(z[6],  c1); z[10] = cmul(z[10], c2);
  z[14] = cmul(z[14], c3); z[3]  = cmul(z[3],  c4);
  c1 = cmul(c1, u4); c2 = cmul(c2, u4); c3 = cmul(c3, u4);
  // k = 13,14,15 -> slots 7,11,15
  z[7]  = cmul(z[7],  c1); z[11] = cmul(z[11], c2); z[15] = cmul(z[15], c3);
}

// Full 1024-pt row: fft16 -> W1024 twiddle -> in-place LDS transpose (wave-
// private, conflict-free XOR swizzle, no s_barrier) -> fft16 -> W64 twiddle ->
// cross-quad radix-4 via DPP -> direct coalesced-segment stores (4x128B/instr).
__device__ __forceinline__ void procrow(float2 z[16], float2* __restrict__ buf,
                                        float2 u1, float2 u2, int lane,
                                        float2* __restrict__ dst) {
  fft16(z);
  twiddle_apply(z, u1);

  // transpose: writer lane n'=4m+p, slot kap -> m*64 + ((p+4kap) ^ ((m&3)<<2))
  //            reader lane l2, reg mm        -> mm*64 + (l2 ^ ((mm&3)<<2))
  // (verified 0 SQ_LDS_BANK_CONFLICT in r3)
  const int m = lane >> 2, p = lane & 3;
  #pragma unroll
  for (int s = 0; s < 16; ++s) {
    const int kap = (s >> 2) | ((s & 3) << 2);
    buf[m * 64 + ((p + 4 * kap) ^ ((m & 3) << 2))] = z[s];
  }
  asm volatile("s_waitcnt lgkmcnt(0)" ::: "memory");
  __builtin_amdgcn_sched_barrier(0);
  #pragma unroll
  for (int mm = 0; mm < 16; ++mm) z[mm] = buf[mm * 64 + (lane ^ ((mm & 3) << 2))];
  asm volatile("s_waitcnt lgkmcnt(0)" ::: "memory");  // reads done before next row reuses buf
  __builtin_amdgcn_sched_barrier(0);

  fft16(z);
  twiddle_apply(z, u2);

  // final radix-4 across quad lanes via DPP
  const float sgn1 = (lane & 2) ? -1.0f : 1.0f;
  const float sgn2 = (lane & 1) ? -1.0f : 1.0f;
  const bool tw3 = ((lane & 3) == 3);
  #pragma unroll
  for (int s = 0; s < 16; ++s) {
    float px = dpp_xor2(z[s].x), py = dpp_xor2(z[s].y);
    float ax = fmaf(sgn1, z[s].x, px), ay = fmaf(sgn1, z[s].y, py);
    float bx = tw3 ? ay : ax;
    float by = tw3 ? -ax : ay;
    float qx = dpp_xor1(bx), qy = dpp_xor1(by);
    z[s].x = fmaf(sgn2, bx, qx);
    z[s].y = fmaf(sgn2, by, qy);
  }

  // store X[kap + 16*t + 256*ur(p)]; per instr: 4 aligned 128B segments
  const int kap = lane >> 2;
  const int ur = ((p & 1) << 1) | (p >> 1);  // bitrev2(p)
  float2* __restrict__ orow = dst + kap + 256 * ur;
  #pragma unroll
  for (int s = 0; s < 16; ++s) {
    const int t = (s >> 2) | ((s & 3) << 2);
    orow[16 * t] = z[s];
  }
}

__global__ __launch_bounds__(TPB, 4) void fft1024_kernel(const float* __restrict__ in,
                                                         float* __restrict__ out,
                                                         int nrows) {
  __shared__ __align__(16) float2 lds[TPB / 64][NFFT];  // 8 KB/wave, wave-private
  const int wv = threadIdx.x >> 6;
  const int lane = threadIdx.x & 63;
  const int r0 = (blockIdx.x * (TPB / 64) + wv) * RPW;
  if (r0 >= nrows) return;

  const float2* __restrict__ xin = reinterpret_cast<const float2*>(in) + (size_t)r0 * NFFT;
  float2* __restrict__ xout = reinterpret_cast<float2*>(out) + (size_t)r0 * NFFT;
  float2* buf = lds[wv];

  // row-invariant twiddle bases (2 sincos per wave total)
  float sn, cs;
  __sincosf((float)lane * (-6.2831853071795864769f / 1024.0f), &sn, &cs);
  const float2 u1 = make_float2(cs, sn);
  __sincosf((float)(lane & 3) * (-6.2831853071795864769f / 64.0f), &sn, &cs);
  const float2 u2 = make_float2(cs, sn);

  // Issue BOTH rows' loads up front; row B's 16 loads stay in flight through
  // row A's entire pipeline (compiler emits counted vmcnt: waits for A only).
  float2 A[16], B[16];
  #pragma unroll
  for (int c = 0; c < 16; ++c) A[c] = xin[lane + 64 * c];       // 512B/instr
  #pragma unroll
  for (int c = 0; c < 16; ++c) B[c] = xin[NFFT + lane + 64 * c];
  procrow(A, buf, u1, u2, lane, xout);
  procrow(B, buf, u1, u2, lane, xout + NFFT);
}

extern "C" void kernel_launch(void* const* d_in, const int* in_sizes, int n_in,
                              void* d_out, int out_size, void* d_ws, size_t ws_size,
                              hipStream_t stream) {
  const float* x = (const float*)d_in[0];
  float* out = (float*)d_out;
  const int rows = in_sizes[0] / (2 * NFFT);   // 16384 rows of 1024 complex
  const int rpb = (TPB / 64) * RPW;            // 8 rows per block
  const int blocks = (rows + rpb - 1) / rpb;   // 2048 blocks
  fft1024_kernel<<<blocks, TPB, 0, stream>>>(x, out, rows);
}